// Round 2
// baseline (557.249 us; speedup 1.0000x reference)
//
#include <hip/hip_runtime.h>
#include <cmath>

// Problem constants
constexpr int B_  = 2;
constexpr int T_  = 512;
constexpr int DM_ = 1024;
constexpr int H_  = 16;
constexpr int DH_ = 64;
constexpr int D_  = 32;
constexpr int R_  = 4;
constexpr int BH_ = B_ * H_;   // 32
constexpr int M_  = B_ * T_;   // 1024 rows for the dense GEMMs

// -------------------------------------------------------------------------
// Kernel 1: fused QKV projection.  C = x(1024x1024) @ {Wq|Wk|Wv}(1024x1024)
// 64x128 tile, BK=8, 256 threads, 4x8 per-thread micro-tile.
// Stores directly into head layout (b,h,t,d).
// -------------------------------------------------------------------------
__global__ __launch_bounds__(256) void qkv_gemm(
    const float* __restrict__ x,
    const float* __restrict__ Wq, const float* __restrict__ Wk,
    const float* __restrict__ Wv,
    float* __restrict__ q_raw, float* __restrict__ k_raw,
    float* __restrict__ v_out)
{
    __shared__ float As[8][64];
    __shared__ float Bs[8][128];
    const int tid = threadIdx.x;
    const int bm  = blockIdx.y * 64;
    const int n0  = blockIdx.x * 128;
    const int which = n0 >> 10;          // 0:q 1:k 2:v (128 divides 1024)
    const int bn  = n0 & 1023;
    const float* W = (which == 0) ? Wq : (which == 1) ? Wk : Wv;
    float* Cout    = (which == 0) ? q_raw : (which == 1) ? k_raw : v_out;

    const int tx = tid & 15;             // 16 col groups x 8 cols
    const int ty = tid >> 4;             // 16 row groups x 4 rows
    const int arow = tid >> 1, akk = (tid & 1) * 4;
    const int bkk  = tid >> 5, bnn = (tid & 31) * 4;

    float acc[4][8] = {};
    for (int k0 = 0; k0 < DM_; k0 += 8) {
        if (tid < 128) {
            float4 a = *(const float4*)&x[(size_t)(bm + arow) * DM_ + k0 + akk];
            As[akk + 0][arow] = a.x; As[akk + 1][arow] = a.y;
            As[akk + 2][arow] = a.z; As[akk + 3][arow] = a.w;
        }
        {
            float4 b = *(const float4*)&W[(size_t)(k0 + bkk) * DM_ + bn + bnn];
            *(float4*)&Bs[bkk][bnn] = b;
        }
        __syncthreads();
#pragma unroll
        for (int kk = 0; kk < 8; ++kk) {
            float4 a4 = *(const float4*)&As[kk][ty * 4];
            float4 b0 = *(const float4*)&Bs[kk][tx * 8];
            float4 b1 = *(const float4*)&Bs[kk][tx * 8 + 4];
            float av[4] = {a4.x, a4.y, a4.z, a4.w};
            float bv[8] = {b0.x, b0.y, b0.z, b0.w, b1.x, b1.y, b1.z, b1.w};
#pragma unroll
            for (int i = 0; i < 4; ++i)
#pragma unroll
                for (int j = 0; j < 8; ++j)
                    acc[i][j] = fmaf(av[i], bv[j], acc[i][j]);
        }
        __syncthreads();
    }
    // store to (b,h,t,d)
#pragma unroll
    for (int i = 0; i < 4; ++i) {
        int m  = bm + ty * 4 + i;
        int bb = m >> 9, t = m & (T_ - 1);
#pragma unroll
        for (int j = 0; j < 8; ++j) {
            int n = bn + tx * 8 + j;
            int h = n >> 6, d = n & 63;
            Cout[(((size_t)bb * H_ + h) * T_ + t) * DH_ + d] = acc[i][j];
        }
    }
}

// -------------------------------------------------------------------------
// Kernel 4 (same shape): output projection, plain row-major store.
// -------------------------------------------------------------------------
__global__ __launch_bounds__(256) void out_gemm(
    const float* __restrict__ A, const float* __restrict__ W,
    float* __restrict__ C)
{
    __shared__ float As[8][64];
    __shared__ float Bs[8][128];
    const int tid = threadIdx.x;
    const int bm  = blockIdx.y * 64;
    const int bn  = blockIdx.x * 128;
    const int tx = tid & 15;
    const int ty = tid >> 4;
    const int arow = tid >> 1, akk = (tid & 1) * 4;
    const int bkk  = tid >> 5, bnn = (tid & 31) * 4;

    float acc[4][8] = {};
    for (int k0 = 0; k0 < DM_; k0 += 8) {
        if (tid < 128) {
            float4 a = *(const float4*)&A[(size_t)(bm + arow) * DM_ + k0 + akk];
            As[akk + 0][arow] = a.x; As[akk + 1][arow] = a.y;
            As[akk + 2][arow] = a.z; As[akk + 3][arow] = a.w;
        }
        {
            float4 b = *(const float4*)&W[(size_t)(k0 + bkk) * DM_ + bn + bnn];
            *(float4*)&Bs[bkk][bnn] = b;
        }
        __syncthreads();
#pragma unroll
        for (int kk = 0; kk < 8; ++kk) {
            float4 a4 = *(const float4*)&As[kk][ty * 4];
            float4 b0 = *(const float4*)&Bs[kk][tx * 8];
            float4 b1 = *(const float4*)&Bs[kk][tx * 8 + 4];
            float av[4] = {a4.x, a4.y, a4.z, a4.w};
            float bv[8] = {b0.x, b0.y, b0.z, b0.w, b1.x, b1.y, b1.z, b1.w};
#pragma unroll
            for (int i = 0; i < 4; ++i)
#pragma unroll
                for (int j = 0; j < 8; ++j)
                    acc[i][j] = fmaf(av[i], bv[j], acc[i][j]);
        }
        __syncthreads();
    }
#pragma unroll
    for (int i = 0; i < 4; ++i) {
        int m = bm + ty * 4 + i;
#pragma unroll
        for (int j = 0; j < 8; ++j) {
            int n = bn + tx * 8 + j;
            C[(size_t)m * DM_ + n] = acc[i][j];
        }
    }
}

// -------------------------------------------------------------------------
// Kernel 2/3: per-row features.  One wave (64 lanes) per (b,h,t) row.
// RoPE (never materialized) -> fm = sigmoid(rope(raw) @ Wm) -> f2 = |fm|^2
// Q-side additionally: U = fm @ Wmetric (128 wide), Uq[r] = sum_d U[d,r]*fm[d]
// -------------------------------------------------------------------------
template <bool QSIDE>
__global__ __launch_bounds__(256) void feat_kernel(
    const float* __restrict__ raw,       // (BH,T,64)
    const float* __restrict__ Wm,        // (64,32)
    const float* __restrict__ Wmetric,   // (32,128)  [QSIDE only]
    float* __restrict__ fm,              // (BH,T,32)
    float* __restrict__ f2,              // (BH,T)
    float* __restrict__ Ug,              // (BH,T,128) [QSIDE only]
    float* __restrict__ Uqg)             // (BH,T,4)   [QSIDE only]
{
    __shared__ float qrs[4][64];
    __shared__ float qms[4][32];
    __shared__ float Us[4][128];
    const int tid  = threadIdx.x;
    const int w    = tid >> 6;
    const int lane = tid & 63;
    const int row  = blockIdx.x * 4 + w;     // 0..BH*T-1
    const int t    = row & (T_ - 1);

    // RoPE: inv_freq[i] = 10000^(-i/32) = exp(-i * ln(10000)/32)
    float rv = raw[(size_t)row * 64 + lane];
    int   fi = lane & 31;
    float ang = (float)t * expf((float)fi * -0.28782313662425575f);
    float s, c;
    sincosf(ang, &s, &c);
    float partner = __shfl_xor(rv, 32);
    float qr = (lane < 32) ? (rv * c - partner * s) : (partner * s + rv * c);
    qrs[w][lane] = qr;
    __syncthreads();

    if (lane < 32) {
        float acc = 0.f;
#pragma unroll 8
        for (int d = 0; d < 64; ++d) acc += qrs[w][d] * Wm[d * 32 + lane];
        float qv = 1.0f / (1.0f + __expf(-acc));
        qms[w][lane] = qv;
        fm[(size_t)row * 32 + lane] = qv;
    }
    __syncthreads();
    if (lane == 0) {
        float acc = 0.f;
#pragma unroll
        for (int m = 0; m < 32; ++m) acc += qms[w][m] * qms[w][m];
        f2[row] = acc;
    }
    if (QSIDE) {
        float a0 = 0.f, a1 = 0.f;
#pragma unroll 8
        for (int m = 0; m < 32; ++m) {
            float qv = qms[w][m];
            a0 += qv * Wmetric[m * 128 + lane];
            a1 += qv * Wmetric[m * 128 + 64 + lane];
        }
        Us[w][lane] = a0; Us[w][64 + lane] = a1;
        Ug[(size_t)row * 128 + lane]      = a0;
        Ug[(size_t)row * 128 + 64 + lane] = a1;
        __syncthreads();
        if (lane < 4) {
            float acc = 0.f;
#pragma unroll
            for (int d = 0; d < 32; ++d) acc += Us[w][d * 4 + lane] * qms[w][d];
            Uqg[(size_t)row * 4 + lane] = acc;
        }
    }
}

// -------------------------------------------------------------------------
// Kernel 5: causal distance scores.
// Block = (bh, i-tile of 32).  Thread (ii, js): fixed i, j loops js..i step 8.
// S[i,j] = -max(q2[i]+k2[j]-2*qm.km + sum_r (Uq[i,r]-U[i,:,r].km[j,:])^2, 0)/temp
// -------------------------------------------------------------------------
__global__ __launch_bounds__(256) void scores_kernel(
    const float* __restrict__ qm, const float* __restrict__ km,
    const float* __restrict__ q2, const float* __restrict__ k2,
    const float* __restrict__ Ug, const float* __restrict__ Uqg,
    const float* __restrict__ temp_p, float* __restrict__ S)
{
    __shared__ float qm_s[32][33];   // +1 pad: fixed-d reads hit distinct banks
    __shared__ float U_s[32][132];   // +4 pad for float4 reads
    __shared__ float Uq_s[32][4];
    __shared__ float q2_s[32];
    const int tid = threadIdx.x;
    const int bh  = blockIdx.y;
    const int i0  = blockIdx.x * 32;

    for (int e = tid; e < 32 * 32; e += 256) {
        int ii = e >> 5, m = e & 31;
        qm_s[ii][m] = qm[((size_t)bh * T_ + i0 + ii) * 32 + m];
    }
    for (int e = tid; e < 32 * 128; e += 256) {
        int ii = e >> 7, n = e & 127;
        U_s[ii][n] = Ug[((size_t)bh * T_ + i0 + ii) * 128 + n];
    }
    if (tid < 128) Uq_s[tid >> 2][tid & 3] = Uqg[((size_t)bh * T_ + i0) * 4 + tid];
    if (tid < 32)  q2_s[tid] = q2[(size_t)bh * T_ + i0 + tid];
    __syncthreads();

    const float inv_temp = 1.0f / fmaxf(temp_p[0], 0.5f);
    const int ii = tid & 31, js = tid >> 5;
    const int i  = i0 + ii;
    const float q2v = q2_s[ii];
    const float uq0 = Uq_s[ii][0], uq1 = Uq_s[ii][1];
    const float uq2 = Uq_s[ii][2], uq3 = Uq_s[ii][3];
    float* Srow = S + ((size_t)bh * T_ + i) * T_;

    for (int j = js; j <= i; j += 8) {
        const float4* kmv = (const float4*)&km[((size_t)bh * T_ + j) * 32];
        float qk = 0.f, u0 = 0.f, u1 = 0.f, u2 = 0.f, u3 = 0.f;
#pragma unroll
        for (int dq = 0; dq < 8; ++dq) {
            float4 kd4 = kmv[dq];
            float  kd[4] = {kd4.x, kd4.y, kd4.z, kd4.w};
#pragma unroll
            for (int dd = 0; dd < 4; ++dd) {
                int d = dq * 4 + dd;
                float kdv = kd[dd];
                qk += qm_s[ii][d] * kdv;
                float4 uu = *(const float4*)&U_s[ii][4 * d];
                u0 = fmaf(uu.x, kdv, u0); u1 = fmaf(uu.y, kdv, u1);
                u2 = fmaf(uu.z, kdv, u2); u3 = fmaf(uu.w, kdv, u3);
            }
        }
        float e0 = uq0 - u0, e1 = uq1 - u1, e2 = uq2 - u2, e3 = uq3 - u3;
        float dist = q2v + k2[(size_t)bh * T_ + j] - 2.f * qk
                   + e0 * e0 + e1 * e1 + e2 * e2 + e3 * e3;
        dist = fmaxf(dist, 0.f);
        Srow[j] = -dist * inv_temp;
    }
}

// -------------------------------------------------------------------------
// Kernel 6: softmax over j<=i, then ctx[i,:] = sum_j p[j] * v[j,:].
// One wave per (bh, i) row.  Writes merged (b,t,c) layout for the Wo GEMM.
// -------------------------------------------------------------------------
__global__ __launch_bounds__(64) void softmax_pv(
    const float* __restrict__ S, const float* __restrict__ v,
    float* __restrict__ ctx)
{
    __shared__ float p_s[T_];
    const int lane = threadIdx.x;
    const int i = blockIdx.x, bh = blockIdx.y;
    const float* Srow = S + ((size_t)bh * T_ + i) * T_;

    float m = -1e30f;
    for (int j = lane; j <= i; j += 64) m = fmaxf(m, Srow[j]);
#pragma unroll
    for (int off = 32; off > 0; off >>= 1) m = fmaxf(m, __shfl_xor(m, off));

    float sum = 0.f;
    for (int j = lane; j <= i; j += 64) {
        float p = __expf(Srow[j] - m);
        p_s[j] = p;
        sum += p;
    }
#pragma unroll
    for (int off = 32; off > 0; off >>= 1) sum += __shfl_xor(sum, off);
    __syncthreads();

    const float inv = 1.0f / sum;
    const float* vbase = v + (size_t)bh * T_ * 64 + lane;
    float acc = 0.f;
    for (int j = 0; j <= i; ++j) acc = fmaf(p_s[j], vbase[(size_t)j * 64], acc);
    int b = bh >> 4, h = bh & 15;
    ctx[((size_t)b * T_ + i) * DM_ + h * 64 + lane] = acc * inv;
}

// -------------------------------------------------------------------------
extern "C" void kernel_launch(void* const* d_in, const int* in_sizes, int n_in,
                              void* d_out, int out_size, void* d_ws, size_t ws_size,
                              hipStream_t stream)
{
    const float* x       = (const float*)d_in[0];
    const float* Wq      = (const float*)d_in[1];
    const float* Wk      = (const float*)d_in[2];
    const float* Wv      = (const float*)d_in[3];
    const float* Wo      = (const float*)d_in[4];
    const float* Wqm     = (const float*)d_in[5];
    const float* Wkm     = (const float*)d_in[6];
    const float* Wmetric = (const float*)d_in[7];
    const float* temp    = (const float*)d_in[8];
    float* out = (float*)d_out;
    float* ws  = (float*)d_ws;

    // workspace layout (floats) — total 14,778,368 floats = 59.1 MB
    float* q_raw = ws;                        // 1,048,576  (B,H,T,64)
    float* k_raw = q_raw + (size_t)BH_ * T_ * DH_;
    float* v     = k_raw + (size_t)BH_ * T_ * DH_;
    float* qm    = v     + (size_t)BH_ * T_ * DH_;
    float* km    = qm    + (size_t)BH_ * T_ * D_;
    float* q2    = km    + (size_t)BH_ * T_ * D_;
    float* k2    = q2    + (size_t)BH_ * T_;
    float* U     = k2    + (size_t)BH_ * T_;
    float* Uq    = U     + (size_t)BH_ * T_ * D_ * R_;
    float* S     = Uq    + (size_t)BH_ * T_ * R_;
    float* ctx   = q_raw;   // q_raw dead after feat kernels; ctx = 1,048,576 floats

    // M = B*T = 1024 rows -> grid.y = 1024/64 = 16  (Round-1 bug: was 32 -> OOB)
    qkv_gemm<<<dim3(24, 16), 256, 0, stream>>>(x, Wq, Wk, Wv, q_raw, k_raw, v);
    feat_kernel<true ><<<BH_ * T_ / 4, 256, 0, stream>>>(q_raw, Wqm, Wmetric, qm, q2, U, Uq);
    feat_kernel<false><<<BH_ * T_ / 4, 256, 0, stream>>>(k_raw, Wkm, nullptr, km, k2, nullptr, nullptr);
    scores_kernel<<<dim3(T_ / 32, BH_), 256, 0, stream>>>(qm, km, q2, k2, U, Uq, temp, S);
    softmax_pv<<<dim3(T_, BH_), 64, 0, stream>>>(S, v, ctx);
    out_gemm<<<dim3(8, 16), 256, 0, stream>>>(ctx, Wo, out);
}

// Round 3
// 441.664 us; speedup vs baseline: 1.2617x; 1.2617x over previous
//
#include <hip/hip_runtime.h>
#include <cmath>

// Problem constants
constexpr int B_  = 2;
constexpr int T_  = 512;
constexpr int DM_ = 1024;
constexpr int H_  = 16;
constexpr int DH_ = 64;
constexpr int D_  = 32;
constexpr int R_  = 4;
constexpr int BH_ = B_ * H_;   // 32

typedef __bf16 bf16x8 __attribute__((ext_vector_type(8)));
typedef float  f32x4  __attribute__((ext_vector_type(4)));
typedef unsigned short u16x8 __attribute__((ext_vector_type(8)));

__device__ __forceinline__ unsigned short f2bf(float f) {
    unsigned u = __float_as_uint(f);
    return (unsigned short)((u + 0x7fffu + ((u >> 16) & 1u)) >> 16);  // RNE
}

__device__ __forceinline__ void gload16(const void* g, void* l) {
    __builtin_amdgcn_global_load_lds(
        (const __attribute__((address_space(1))) void*)g,
        (__attribute__((address_space(3))) void*)l, 16, 0, 0);
}

// -------------------------------------------------------------------------
// Convert x (1M fp32) -> bf16 row-major.  4 elems/thread.
// -------------------------------------------------------------------------
__global__ __launch_bounds__(256) void convert_x_bf16(
    const float* __restrict__ in, unsigned short* __restrict__ out)
{
    int idx = (blockIdx.x * 256 + threadIdx.x) * 4;
    float4 v = *(const float4*)&in[idx];
    ushort4 o = { f2bf(v.x), f2bf(v.y), f2bf(v.z), f2bf(v.w) };
    *(ushort4*)&out[idx] = o;
}

// -------------------------------------------------------------------------
// Transpose+convert W (1024x1024 fp32, K-major) -> out (N x K bf16).
// 64x64 LDS tile.  grid.z selects among up to 3 matrices.
// -------------------------------------------------------------------------
__global__ __launch_bounds__(256) void transpose_w_bf16(
    const float* __restrict__ W0, const float* __restrict__ W1,
    const float* __restrict__ W2,
    unsigned short* __restrict__ O0, unsigned short* __restrict__ O1,
    unsigned short* __restrict__ O2)
{
    __shared__ __align__(16) unsigned short Ls[64][72];  // +8 pad, row=144B (16B mult)
    const int z = blockIdx.z;
    const float* W = (z == 0) ? W0 : (z == 1) ? W1 : W2;
    unsigned short* O = (z == 0) ? O0 : (z == 1) ? O1 : O2;
    const int t  = threadIdx.x;
    const int k0 = blockIdx.x * 64;
    const int n0 = blockIdx.y * 64;
#pragma unroll
    for (int it = 0; it < 4; ++it) {
        int r = it * 16 + (t >> 4);
        int c = (t & 15) * 4;
        float4 v4 = *(const float4*)&W[(size_t)(k0 + r) * DM_ + n0 + c];
        Ls[c + 0][r] = f2bf(v4.x); Ls[c + 1][r] = f2bf(v4.y);
        Ls[c + 2][r] = f2bf(v4.z); Ls[c + 3][r] = f2bf(v4.w);
    }
    __syncthreads();
#pragma unroll
    for (int it = 0; it < 2; ++it) {
        int nl = it * 32 + (t >> 3);
        int kc = (t & 7) * 8;
        *(u16x8*)&O[(size_t)(n0 + nl) * DM_ + k0 + kc] = *(const u16x8*)&Ls[nl][kc];
    }
}

// -------------------------------------------------------------------------
// bf16 MFMA GEMM core: 128x128 tile, BK=32, 256 thr (4 waves 2x2), m97 style.
// A: M x K row-major bf16.  Bt: N x K row-major bf16 (i.e. B transposed).
// EPI==0: scatter C into q/k/v head layout.  EPI==1: plain fp32 C (M x 1024).
// -------------------------------------------------------------------------
template <int EPI>
__global__ __launch_bounds__(256) void mfma_gemm(
    const unsigned short* __restrict__ A,
    const unsigned short* __restrict__ Bt0,
    const unsigned short* __restrict__ Bt1,
    const unsigned short* __restrict__ Bt2,
    float* __restrict__ C0, float* __restrict__ C1, float* __restrict__ C2)
{
    __shared__ __align__(16) unsigned short As[128 * 32];
    __shared__ __align__(16) unsigned short Bs[128 * 32];
    const int tid  = threadIdx.x;
    const int lane = tid & 63;
    const int w    = tid >> 6;
    const int wm   = (w & 1) * 64;
    const int wn   = (w >> 1) * 64;

    const int bm = blockIdx.y * 128;
    int bn, which = 0;
    const unsigned short* Bt;
    float* C;
    if (EPI == 0) {
        which = blockIdx.x >> 3;                 // 0:q 1:k 2:v
        bn    = (blockIdx.x & 7) * 128;
        Bt = (which == 0) ? Bt0 : (which == 1) ? Bt1 : Bt2;
        C  = (which == 0) ? C0  : (which == 1) ? C1  : C2;
    } else {
        bn = blockIdx.x * 128;
        Bt = Bt0; C = C0;
    }

    f32x4 acc[4][4] = {};

    const int sr = tid >> 2;            // staging row 0..63
    const int sc = (tid & 3) * 8;       // 16B chunk within 64B row
    const unsigned short* Ap = A  + (size_t)(bm + sr) * DM_ + sc;
    const unsigned short* Bp = Bt + (size_t)(bn + sr) * DM_ + sc;
    unsigned short* AsP = &As[sr * 32 + sc];
    unsigned short* BsP = &Bs[sr * 32 + sc];

    const int fr = lane & 15;
    const int fq = (lane >> 4) * 8;

    for (int k0 = 0; k0 < DM_; k0 += 32) {
        gload16(Ap + k0,              AsP);
        gload16(Ap + 64 * DM_ + k0,   AsP + 64 * 32);
        gload16(Bp + k0,              BsP);
        gload16(Bp + 64 * DM_ + k0,   BsP + 64 * 32);
        __syncthreads();
        bf16x8 af[4], bfr[4];
#pragma unroll
        for (int i = 0; i < 4; ++i) {
            af[i]  = *(const bf16x8*)&As[(wm + i * 16 + fr) * 32 + fq];
            bfr[i] = *(const bf16x8*)&Bs[(wn + i * 16 + fr) * 32 + fq];
        }
#pragma unroll
        for (int mi = 0; mi < 4; ++mi)
#pragma unroll
            for (int ni = 0; ni < 4; ++ni)
                acc[mi][ni] = __builtin_amdgcn_mfma_f32_16x16x32_bf16(
                    af[mi], bfr[ni], acc[mi][ni], 0, 0, 0);
        __syncthreads();
    }

#pragma unroll
    for (int mi = 0; mi < 4; ++mi)
#pragma unroll
        for (int ni = 0; ni < 4; ++ni) {
            f32x4 a = acc[mi][ni];
            int col = bn + wn + ni * 16 + (lane & 15);
#pragma unroll
            for (int r = 0; r < 4; ++r) {
                int row = bm + wm + mi * 16 + (lane >> 4) * 4 + r;
                if (EPI == 0) {
                    int h = col >> 6, d = col & 63;
                    int bb = row >> 9, tt = row & (T_ - 1);
                    C[(((size_t)bb * H_ + h) * T_ + tt) * DH_ + d] = a[r];
                } else {
                    C[(size_t)row * DM_ + col] = a[r];
                }
            }
        }
}

// -------------------------------------------------------------------------
// Per-row features (unchanged from Round 2).
// -------------------------------------------------------------------------
template <bool QSIDE>
__global__ __launch_bounds__(256) void feat_kernel(
    const float* __restrict__ raw, const float* __restrict__ Wm,
    const float* __restrict__ Wmetric,
    float* __restrict__ fm, float* __restrict__ f2,
    float* __restrict__ Ug, float* __restrict__ Uqg)
{
    __shared__ float qrs[4][64];
    __shared__ float qms[4][32];
    __shared__ float Us[4][128];
    const int tid  = threadIdx.x;
    const int w    = tid >> 6;
    const int lane = tid & 63;
    const int row  = blockIdx.x * 4 + w;
    const int t    = row & (T_ - 1);

    float rv = raw[(size_t)row * 64 + lane];
    int   fi = lane & 31;
    float ang = (float)t * expf((float)fi * -0.28782313662425575f);
    float s, c;
    sincosf(ang, &s, &c);
    float partner = __shfl_xor(rv, 32);
    float qr = (lane < 32) ? (rv * c - partner * s) : (partner * s + rv * c);
    qrs[w][lane] = qr;
    __syncthreads();

    if (lane < 32) {
        float acc = 0.f;
#pragma unroll 8
        for (int d = 0; d < 64; ++d) acc += qrs[w][d] * Wm[d * 32 + lane];
        float qv = 1.0f / (1.0f + __expf(-acc));
        qms[w][lane] = qv;
        fm[(size_t)row * 32 + lane] = qv;
    }
    __syncthreads();
    if (lane == 0) {
        float acc = 0.f;
#pragma unroll
        for (int m = 0; m < 32; ++m) acc += qms[w][m] * qms[w][m];
        f2[row] = acc;
    }
    if (QSIDE) {
        float a0 = 0.f, a1 = 0.f;
#pragma unroll 8
        for (int m = 0; m < 32; ++m) {
            float qv = qms[w][m];
            a0 += qv * Wmetric[m * 128 + lane];
            a1 += qv * Wmetric[m * 128 + 64 + lane];
        }
        Us[w][lane] = a0; Us[w][64 + lane] = a1;
        Ug[(size_t)row * 128 + lane]      = a0;
        Ug[(size_t)row * 128 + 64 + lane] = a1;
        __syncthreads();
        if (lane < 4) {
            float acc = 0.f;
#pragma unroll
            for (int d = 0; d < 32; ++d) acc += Us[w][d * 4 + lane] * qms[w][d];
            Uqg[(size_t)row * 4 + lane] = acc;
        }
    }
}

// -------------------------------------------------------------------------
// Causal distance scores (unchanged from Round 2).
// -------------------------------------------------------------------------
__global__ __launch_bounds__(256) void scores_kernel(
    const float* __restrict__ qm, const float* __restrict__ km,
    const float* __restrict__ q2, const float* __restrict__ k2,
    const float* __restrict__ Ug, const float* __restrict__ Uqg,
    const float* __restrict__ temp_p, float* __restrict__ S)
{
    __shared__ float qm_s[32][33];
    __shared__ float U_s[32][132];
    __shared__ float Uq_s[32][4];
    __shared__ float q2_s[32];
    const int tid = threadIdx.x;
    const int bh  = blockIdx.y;
    const int i0  = blockIdx.x * 32;

    for (int e = tid; e < 32 * 32; e += 256) {
        int ii = e >> 5, m = e & 31;
        qm_s[ii][m] = qm[((size_t)bh * T_ + i0 + ii) * 32 + m];
    }
    for (int e = tid; e < 32 * 128; e += 256) {
        int ii = e >> 7, n = e & 127;
        U_s[ii][n] = Ug[((size_t)bh * T_ + i0 + ii) * 128 + n];
    }
    if (tid < 128) Uq_s[tid >> 2][tid & 3] = Uqg[((size_t)bh * T_ + i0) * 4 + tid];
    if (tid < 32)  q2_s[tid] = q2[(size_t)bh * T_ + i0 + tid];
    __syncthreads();

    const float inv_temp = 1.0f / fmaxf(temp_p[0], 0.5f);
    const int ii = tid & 31, js = tid >> 5;
    const int i  = i0 + ii;
    const float q2v = q2_s[ii];
    const float uq0 = Uq_s[ii][0], uq1 = Uq_s[ii][1];
    const float uq2 = Uq_s[ii][2], uq3 = Uq_s[ii][3];
    float* Srow = S + ((size_t)bh * T_ + i) * T_;

    for (int j = js; j <= i; j += 8) {
        const float4* kmv = (const float4*)&km[((size_t)bh * T_ + j) * 32];
        float qk = 0.f, u0 = 0.f, u1 = 0.f, u2 = 0.f, u3 = 0.f;
#pragma unroll
        for (int dq = 0; dq < 8; ++dq) {
            float4 kd4 = kmv[dq];
            float  kd[4] = {kd4.x, kd4.y, kd4.z, kd4.w};
#pragma unroll
            for (int dd = 0; dd < 4; ++dd) {
                int d = dq * 4 + dd;
                float kdv = kd[dd];
                qk += qm_s[ii][d] * kdv;
                float4 uu = *(const float4*)&U_s[ii][4 * d];
                u0 = fmaf(uu.x, kdv, u0); u1 = fmaf(uu.y, kdv, u1);
                u2 = fmaf(uu.z, kdv, u2); u3 = fmaf(uu.w, kdv, u3);
            }
        }
        float e0 = uq0 - u0, e1 = uq1 - u1, e2 = uq2 - u2, e3 = uq3 - u3;
        float dist = q2v + k2[(size_t)bh * T_ + j] - 2.f * qk
                   + e0 * e0 + e1 * e1 + e2 * e2 + e3 * e3;
        dist = fmaxf(dist, 0.f);
        Srow[j] = -dist * inv_temp;
    }
}

// -------------------------------------------------------------------------
// Softmax + PV: 256 threads (4 waves); waves split j; LDS-reduce partials.
// Writes ctx as bf16 (b,t,c) ready to be GEMM A-operand.
// -------------------------------------------------------------------------
__global__ __launch_bounds__(256) void softmax_pv(
    const float* __restrict__ S, const float* __restrict__ v,
    unsigned short* __restrict__ ctxb)
{
    __shared__ float p_s[T_];
    __shared__ float red[8];
    __shared__ float pv[4][64];
    const int tid = threadIdx.x, lane = tid & 63, w = tid >> 6;
    const int i = blockIdx.x, bh = blockIdx.y;
    const float* Srow = S + ((size_t)bh * T_ + i) * T_;

    float m = -1e30f;
    for (int j = tid; j <= i; j += 256) m = fmaxf(m, Srow[j]);
#pragma unroll
    for (int off = 32; off > 0; off >>= 1) m = fmaxf(m, __shfl_xor(m, off));
    if (lane == 0) red[w] = m;
    __syncthreads();
    m = fmaxf(fmaxf(red[0], red[1]), fmaxf(red[2], red[3]));

    float sum = 0.f;
    for (int j = tid; j <= i; j += 256) {
        float p = __expf(Srow[j] - m);
        p_s[j] = p;
        sum += p;
    }
#pragma unroll
    for (int off = 32; off > 0; off >>= 1) sum += __shfl_xor(sum, off);
    if (lane == 0) red[4 + w] = sum;
    __syncthreads();
    sum = red[4] + red[5] + red[6] + red[7];

    float acc = 0.f;
    const float* vb = v + (size_t)bh * T_ * 64 + lane;
    for (int j = w; j <= i; j += 4) acc = fmaf(p_s[j], vb[(size_t)j * 64], acc);
    pv[w][lane] = acc;
    __syncthreads();
    if (tid < 64) {
        float r = (pv[0][tid] + pv[1][tid] + pv[2][tid] + pv[3][tid]) / sum;
        int b = bh >> 4, h = bh & 15;
        ctxb[((size_t)b * T_ + i) * DM_ + h * 64 + tid] = f2bf(r);
    }
}

// -------------------------------------------------------------------------
extern "C" void kernel_launch(void* const* d_in, const int* in_sizes, int n_in,
                              void* d_out, int out_size, void* d_ws, size_t ws_size,
                              hipStream_t stream)
{
    const float* x       = (const float*)d_in[0];
    const float* Wq      = (const float*)d_in[1];
    const float* Wk      = (const float*)d_in[2];
    const float* Wv      = (const float*)d_in[3];
    const float* Wo      = (const float*)d_in[4];
    const float* Wqm     = (const float*)d_in[5];
    const float* Wkm     = (const float*)d_in[6];
    const float* Wmetric = (const float*)d_in[7];
    const float* temp    = (const float*)d_in[8];
    float* out = (float*)d_out;
    float* ws  = (float*)d_ws;

    // fp32 workspace layout (floats), total ~56.4 MB — same as Round 2
    float* q_raw = ws;
    float* k_raw = q_raw + (size_t)BH_ * T_ * DH_;
    float* v     = k_raw + (size_t)BH_ * T_ * DH_;
    float* qm    = v     + (size_t)BH_ * T_ * DH_;
    float* km    = qm    + (size_t)BH_ * T_ * D_;
    float* q2    = km    + (size_t)BH_ * T_ * D_;
    float* k2    = q2    + (size_t)BH_ * T_;
    float* U     = k2    + (size_t)BH_ * T_;
    float* Uq    = U     + (size_t)BH_ * T_ * D_ * R_;
    float* S     = Uq    + (size_t)BH_ * T_ * R_;

    // bf16 scratch overlapped into dead regions (zero extra workspace):
    //  - xb, Wq/Wk/Wv bf16-T live in S (S written only later by scores)
    //  - Wo bf16-T converted AFTER softmax_pv has consumed S
    //  - ctx bf16 lives in q_raw (dead after feat kernels)
    unsigned short* xb  = (unsigned short*)S;
    unsigned short* wqb = xb  + (size_t)DM_ * DM_;
    unsigned short* wkb = wqb + (size_t)DM_ * DM_;
    unsigned short* wvb = wkb + (size_t)DM_ * DM_;
    unsigned short* wob = (unsigned short*)S;
    unsigned short* ctxb = (unsigned short*)q_raw;

    convert_x_bf16<<<DM_ * DM_ / 1024, 256, 0, stream>>>(x, xb);
    transpose_w_bf16<<<dim3(16, 16, 3), 256, 0, stream>>>(Wq, Wk, Wv, wqb, wkb, wvb);
    mfma_gemm<0><<<dim3(24, 8), 256, 0, stream>>>(xb, wqb, wkb, wvb, q_raw, k_raw, v);
    feat_kernel<true ><<<BH_ * T_ / 4, 256, 0, stream>>>(q_raw, Wqm, Wmetric, qm, q2, U, Uq);
    feat_kernel<false><<<BH_ * T_ / 4, 256, 0, stream>>>(k_raw, Wkm, nullptr, km, k2, nullptr, nullptr);
    scores_kernel<<<dim3(T_ / 32, BH_), 256, 0, stream>>>(qm, km, q2, k2, U, Uq, temp, S);
    softmax_pv<<<dim3(T_, BH_), 256, 0, stream>>>(S, v, ctxb);
    transpose_w_bf16<<<dim3(16, 16, 1), 256, 0, stream>>>(Wo, Wo, Wo, wob, wob, wob);
    mfma_gemm<1><<<dim3(8, 8), 256, 0, stream>>>(ctxb, wob, nullptr, nullptr, out, nullptr, nullptr);
}

// Round 5
// 277.614 us; speedup vs baseline: 2.0073x; 1.5909x over previous
//
#include <hip/hip_runtime.h>
#include <cmath>

// Problem constants
constexpr int B_  = 2;
constexpr int T_  = 512;
constexpr int DM_ = 1024;
constexpr int H_  = 16;
constexpr int DH_ = 64;
constexpr int D_  = 32;
constexpr int R_  = 4;
constexpr int BH_ = B_ * H_;   // 32

typedef __bf16 bf16x8 __attribute__((ext_vector_type(8)));
typedef float  f32x4  __attribute__((ext_vector_type(4)));
typedef unsigned short u16x8 __attribute__((ext_vector_type(8)));

__device__ __forceinline__ unsigned short f2bf(float f) {
    unsigned u = __float_as_uint(f);
    return (unsigned short)((u + 0x7fffu + ((u >> 16) & 1u)) >> 16);  // RNE
}

__device__ __forceinline__ void gload16(const void* g, void* l) {
    __builtin_amdgcn_global_load_lds(
        (const __attribute__((address_space(1))) void*)g,
        (__attribute__((address_space(3))) void*)l, 16, 0, 0);
}

// -------------------------------------------------------------------------
// Convert x (1M fp32) -> bf16 row-major.
// -------------------------------------------------------------------------
__global__ __launch_bounds__(256) void convert_x_bf16(
    const float* __restrict__ in, unsigned short* __restrict__ out)
{
    int idx = (blockIdx.x * 256 + threadIdx.x) * 4;
    float4 v = *(const float4*)&in[idx];
    ushort4 o = { f2bf(v.x), f2bf(v.y), f2bf(v.z), f2bf(v.w) };
    *(ushort4*)&out[idx] = o;
}

// -------------------------------------------------------------------------
// Transpose+convert W (1024x1024 fp32, K-major) -> out (N x K bf16).
// -------------------------------------------------------------------------
__global__ __launch_bounds__(256) void transpose_w_bf16(
    const float* __restrict__ W0, const float* __restrict__ W1,
    const float* __restrict__ W2,
    unsigned short* __restrict__ O0, unsigned short* __restrict__ O1,
    unsigned short* __restrict__ O2)
{
    __shared__ __align__(16) unsigned short Ls[64][72];
    const int z = blockIdx.z;
    const float* W = (z == 0) ? W0 : (z == 1) ? W1 : W2;
    unsigned short* O = (z == 0) ? O0 : (z == 1) ? O1 : O2;
    const int t  = threadIdx.x;
    const int k0 = blockIdx.x * 64;
    const int n0 = blockIdx.y * 64;
#pragma unroll
    for (int it = 0; it < 4; ++it) {
        int r = it * 16 + (t >> 4);
        int c = (t & 15) * 4;
        float4 v4 = *(const float4*)&W[(size_t)(k0 + r) * DM_ + n0 + c];
        Ls[c + 0][r] = f2bf(v4.x); Ls[c + 1][r] = f2bf(v4.y);
        Ls[c + 2][r] = f2bf(v4.z); Ls[c + 3][r] = f2bf(v4.w);
    }
    __syncthreads();
#pragma unroll
    for (int it = 0; it < 2; ++it) {
        int nl = it * 32 + (t >> 3);
        int kc = (t & 7) * 8;
        *(u16x8*)&O[(size_t)(n0 + nl) * DM_ + k0 + kc] = *(const u16x8*)&Ls[nl][kc];
    }
}

// -------------------------------------------------------------------------
// bf16 MFMA GEMM core (m97 style): 128x128 tile, BK=32, 256 thr.
// EPI==0: scatter C into q/k/v head layout.  EPI==1: plain fp32 C.
// -------------------------------------------------------------------------
template <int EPI>
__global__ __launch_bounds__(256) void mfma_gemm(
    const unsigned short* __restrict__ A,
    const unsigned short* __restrict__ Bt0,
    const unsigned short* __restrict__ Bt1,
    const unsigned short* __restrict__ Bt2,
    float* __restrict__ C0, float* __restrict__ C1, float* __restrict__ C2)
{
    __shared__ __align__(16) unsigned short As[128 * 32];
    __shared__ __align__(16) unsigned short Bs[128 * 32];
    const int tid  = threadIdx.x;
    const int lane = tid & 63;
    const int w    = tid >> 6;
    const int wm   = (w & 1) * 64;
    const int wn   = (w >> 1) * 64;

    const int bm = blockIdx.y * 128;
    int bn;
    const unsigned short* Bt;
    float* C;
    if (EPI == 0) {
        int which = blockIdx.x >> 3;
        bn    = (blockIdx.x & 7) * 128;
        Bt = (which == 0) ? Bt0 : (which == 1) ? Bt1 : Bt2;
        C  = (which == 0) ? C0  : (which == 1) ? C1  : C2;
    } else {
        bn = blockIdx.x * 128;
        Bt = Bt0; C = C0;
    }

    f32x4 acc[4][4] = {};
    const int sr = tid >> 2;
    const int sc = (tid & 3) * 8;
    const unsigned short* Ap = A  + (size_t)(bm + sr) * DM_ + sc;
    const unsigned short* Bp = Bt + (size_t)(bn + sr) * DM_ + sc;
    unsigned short* AsP = &As[sr * 32 + sc];
    unsigned short* BsP = &Bs[sr * 32 + sc];
    const int fr = lane & 15;
    const int fq = (lane >> 4) * 8;

    for (int k0 = 0; k0 < DM_; k0 += 32) {
        gload16(Ap + k0,              AsP);
        gload16(Ap + 64 * DM_ + k0,   AsP + 64 * 32);
        gload16(Bp + k0,              BsP);
        gload16(Bp + 64 * DM_ + k0,   BsP + 64 * 32);
        __syncthreads();
        bf16x8 af[4], bfr[4];
#pragma unroll
        for (int i = 0; i < 4; ++i) {
            af[i]  = *(const bf16x8*)&As[(wm + i * 16 + fr) * 32 + fq];
            bfr[i] = *(const bf16x8*)&Bs[(wn + i * 16 + fr) * 32 + fq];
        }
#pragma unroll
        for (int mi = 0; mi < 4; ++mi)
#pragma unroll
            for (int ni = 0; ni < 4; ++ni)
                acc[mi][ni] = __builtin_amdgcn_mfma_f32_16x16x32_bf16(
                    af[mi], bfr[ni], acc[mi][ni], 0, 0, 0);
        __syncthreads();
    }

#pragma unroll
    for (int mi = 0; mi < 4; ++mi)
#pragma unroll
        for (int ni = 0; ni < 4; ++ni) {
            f32x4 a = acc[mi][ni];
            int col = bn + wn + ni * 16 + (lane & 15);
#pragma unroll
            for (int r = 0; r < 4; ++r) {
                int row = bm + wm + mi * 16 + (lane >> 4) * 4 + r;
                if (EPI == 0) {
                    int h = col >> 6, d = col & 63;
                    int bb = row >> 9, tt = row & (T_ - 1);
                    C[(((size_t)bb * H_ + h) * T_ + tt) * DH_ + d] = a[r];
                } else {
                    C[(size_t)row * DM_ + col] = a[r];
                }
            }
        }
}

// -------------------------------------------------------------------------
// Per-row features (unchanged).
// -------------------------------------------------------------------------
template <bool QSIDE>
__global__ __launch_bounds__(256) void feat_kernel(
    const float* __restrict__ raw, const float* __restrict__ Wm,
    const float* __restrict__ Wmetric,
    float* __restrict__ fm, float* __restrict__ f2,
    float* __restrict__ Ug, float* __restrict__ Uqg)
{
    __shared__ float qrs[4][64];
    __shared__ float qms[4][32];
    __shared__ float Us[4][128];
    const int tid  = threadIdx.x;
    const int w    = tid >> 6;
    const int lane = tid & 63;
    const int row  = blockIdx.x * 4 + w;
    const int t    = row & (T_ - 1);

    float rv = raw[(size_t)row * 64 + lane];
    int   fi = lane & 31;
    float ang = (float)t * expf((float)fi * -0.28782313662425575f);
    float s, c;
    sincosf(ang, &s, &c);
    float partner = __shfl_xor(rv, 32);
    float qr = (lane < 32) ? (rv * c - partner * s) : (partner * s + rv * c);
    qrs[w][lane] = qr;
    __syncthreads();

    if (lane < 32) {
        float acc = 0.f;
#pragma unroll 8
        for (int d = 0; d < 64; ++d) acc += qrs[w][d] * Wm[d * 32 + lane];
        float qv = 1.0f / (1.0f + __expf(-acc));
        qms[w][lane] = qv;
        fm[(size_t)row * 32 + lane] = qv;
    }
    __syncthreads();
    if (lane == 0) {
        float acc = 0.f;
#pragma unroll
        for (int m = 0; m < 32; ++m) acc += qms[w][m] * qms[w][m];
        f2[row] = acc;
    }
    if (QSIDE) {
        float a0 = 0.f, a1 = 0.f;
#pragma unroll 8
        for (int m = 0; m < 32; ++m) {
            float qv = qms[w][m];
            a0 += qv * Wmetric[m * 128 + lane];
            a1 += qv * Wmetric[m * 128 + 64 + lane];
        }
        Us[w][lane] = a0; Us[w][64 + lane] = a1;
        Ug[(size_t)row * 128 + lane]      = a0;
        Ug[(size_t)row * 128 + 64 + lane] = a1;
        __syncthreads();
        if (lane < 4) {
            float acc = 0.f;
#pragma unroll
            for (int d = 0; d < 32; ++d) acc += Us[w][d * 4 + lane] * qms[w][d];
            Uqg[(size_t)row * 4 + lane] = acc;
        }
    }
}

// -------------------------------------------------------------------------
// Fused flash-style attention: scores + online softmax + PV, no S buffer.
// Block = (i-tile of 32, bh).  256 threads.
// Scores phase: thread (ii=tid&31, js=tid>>5) computes jj = js*4 + {0..3}.
// Update phase: thread (ii=tid>>3, ds=tid&7) owns O[ii][ds*8 .. ds*8+7];
//   m/l carried in registers (redundant across the 8 ds threads of an ii).
// -------------------------------------------------------------------------
__global__ __launch_bounds__(256) void fused_attn(
    const float* __restrict__ qm, const float* __restrict__ km,
    const float* __restrict__ q2, const float* __restrict__ k2,
    const float* __restrict__ Ug, const float* __restrict__ Uqg,
    const float* __restrict__ temp_p, const float* __restrict__ v,
    unsigned short* __restrict__ ctxb)
{
    __shared__ __align__(16) float qm_s[32][33];
    __shared__ __align__(16) float U_s[32][132];
    __shared__ __align__(16) float Uq_s[32][4];
    __shared__ float q2_s[32];
    __shared__ __align__(16) float kmT_s[32][36];  // [d][jj]
    __shared__ float k2_s[32];
    __shared__ __align__(16) float v_s[32][64];    // [jj][dh]
    __shared__ float s_tile[32][33];

    const int tid = threadIdx.x;
    const int bh  = blockIdx.y;
    const int i0  = blockIdx.x * 32;

    // ---- one-time staging of the i-tile ----
    for (int e = tid; e < 32 * 32; e += 256) {
        int ii = e >> 5, m = e & 31;
        qm_s[ii][m] = qm[((size_t)bh * T_ + i0 + ii) * 32 + m];
    }
    for (int e = tid; e < 32 * 128; e += 256) {
        int ii = e >> 7, n = e & 127;
        U_s[ii][n] = Ug[((size_t)bh * T_ + i0 + ii) * 128 + n];
    }
    if (tid < 128) Uq_s[tid >> 2][tid & 3] = Uqg[((size_t)bh * T_ + i0) * 4 + tid];
    if (tid < 32)  q2_s[tid] = q2[(size_t)bh * T_ + i0 + tid];

    const float inv_temp = 1.0f / fmaxf(temp_p[0], 0.5f);

    // scores-phase identity
    const int ii_s = tid & 31, js = tid >> 5;
    // update-phase identity
    const int ii_u = tid >> 3, ds = tid & 7;

    float m_run = -1e30f, l_run = 0.f;
    float O[8] = {};

    const int ntile = (i0 >> 5) + 1;
    for (int jt = 0; jt < ntile; ++jt) {
        const int j0 = jt * 32;
        __syncthreads();   // protect previous tile's LDS from overwrite
        // ---- stage km (transposed), k2, v tile ----
        {
            int jr = tid >> 3, c4 = (tid & 7) * 4;
            float4 g = *(const float4*)&km[((size_t)bh * T_ + j0 + jr) * 32 + c4];
            kmT_s[c4 + 0][jr] = g.x; kmT_s[c4 + 1][jr] = g.y;
            kmT_s[c4 + 2][jr] = g.z; kmT_s[c4 + 3][jr] = g.w;
        }
        if (tid < 32) k2_s[tid] = k2[(size_t)bh * T_ + j0 + tid];
        // v tile: 32 rows x 64 cols = 512 float4, 16 float4 per row
        //   (Round-4 bug: used >>3/&7 -> rows 0..63, OOB into s_tile)
#pragma unroll
        for (int e = tid; e < 512; e += 256) {
            int jr = e >> 4, c4 = (e & 15) * 4;
            *(float4*)&v_s[jr][c4] =
                *(const float4*)&v[((size_t)bh * T_ + j0 + jr) * 64 + c4];
        }
        __syncthreads();

        // ---- scores: 4 consecutive jj per thread ----
        {
            float qk[4] = {};
            float ur[4][4] = {};
#pragma unroll 8
            for (int d = 0; d < 32; ++d) {
                float4 kd = *(const float4*)&kmT_s[d][js * 4];
                float  qv = qm_s[ii_s][d];
                float4 uv = *(const float4*)&U_s[ii_s][4 * d];
                float  kc[4] = {kd.x, kd.y, kd.z, kd.w};
#pragma unroll
                for (int c = 0; c < 4; ++c) {
                    qk[c] = fmaf(qv, kc[c], qk[c]);
                    ur[c][0] = fmaf(uv.x, kc[c], ur[c][0]);
                    ur[c][1] = fmaf(uv.y, kc[c], ur[c][1]);
                    ur[c][2] = fmaf(uv.z, kc[c], ur[c][2]);
                    ur[c][3] = fmaf(uv.w, kc[c], ur[c][3]);
                }
            }
            const float q2v = q2_s[ii_s];
            const float uq0 = Uq_s[ii_s][0], uq1 = Uq_s[ii_s][1];
            const float uq2 = Uq_s[ii_s][2], uq3 = Uq_s[ii_s][3];
#pragma unroll
            for (int c = 0; c < 4; ++c) {
                int jj = js * 4 + c;
                float e0 = uq0 - ur[c][0], e1 = uq1 - ur[c][1];
                float e2 = uq2 - ur[c][2], e3 = uq3 - ur[c][3];
                float dist = q2v + k2_s[jj] - 2.f * qk[c]
                           + e0 * e0 + e1 * e1 + e2 * e2 + e3 * e3;
                float s = -fmaxf(dist, 0.f) * inv_temp;
                if (j0 + jj > i0 + ii_s) s = -1e30f;
                s_tile[ii_s][jj] = s;
            }
        }
        __syncthreads();

        // ---- online softmax + PV ----
        {
            float mt = -1e30f;
#pragma unroll 8
            for (int jj = 0; jj < 32; ++jj) mt = fmaxf(mt, s_tile[ii_u][jj]);
            float mnew  = fmaxf(m_run, mt);
            float alpha = __expf(m_run - mnew);
            l_run *= alpha;
#pragma unroll
            for (int dd = 0; dd < 8; ++dd) O[dd] *= alpha;
#pragma unroll 4
            for (int jj = 0; jj < 32; ++jj) {
                float p = __expf(s_tile[ii_u][jj] - mnew);
                l_run += p;
                float4 v0 = *(const float4*)&v_s[jj][ds * 8];
                float4 v1 = *(const float4*)&v_s[jj][ds * 8 + 4];
                O[0] = fmaf(p, v0.x, O[0]); O[1] = fmaf(p, v0.y, O[1]);
                O[2] = fmaf(p, v0.z, O[2]); O[3] = fmaf(p, v0.w, O[3]);
                O[4] = fmaf(p, v1.x, O[4]); O[5] = fmaf(p, v1.y, O[5]);
                O[6] = fmaf(p, v1.z, O[6]); O[7] = fmaf(p, v1.w, O[7]);
            }
            m_run = mnew;
        }
    }

    // ---- epilogue: normalize, write ctx bf16 (b,t,c) ----
    const float inv_l = 1.0f / l_run;
    const int i = i0 + ii_u;
    const int b = bh >> 4, h = bh & 15;
    u16x8 o;
#pragma unroll
    for (int dd = 0; dd < 8; ++dd) o[dd] = f2bf(O[dd] * inv_l);
    *(u16x8*)&ctxb[((size_t)b * T_ + i) * DM_ + h * 64 + ds * 8] = o;
}

// -------------------------------------------------------------------------
extern "C" void kernel_launch(void* const* d_in, const int* in_sizes, int n_in,
                              void* d_out, int out_size, void* d_ws, size_t ws_size,
                              hipStream_t stream)
{
    const float* x       = (const float*)d_in[0];
    const float* Wq      = (const float*)d_in[1];
    const float* Wk      = (const float*)d_in[2];
    const float* Wv      = (const float*)d_in[3];
    const float* Wo      = (const float*)d_in[4];
    const float* Wqm     = (const float*)d_in[5];
    const float* Wkm     = (const float*)d_in[6];
    const float* Wmetric = (const float*)d_in[7];
    const float* temp    = (const float*)d_in[8];
    float* out = (float*)d_out;
    float* ws  = (float*)d_ws;

    // fp32 workspace (floats); no S buffer anymore
    float* q_raw = ws;                                  // 1,048,576
    float* k_raw = q_raw + (size_t)BH_ * T_ * DH_;      // 1,048,576
    float* v     = k_raw + (size_t)BH_ * T_ * DH_;      // 1,048,576
    float* qm    = v     + (size_t)BH_ * T_ * DH_;      //   524,288
    float* km    = qm    + (size_t)BH_ * T_ * D_;       //   524,288
    float* q2    = km    + (size_t)BH_ * T_ * D_;       //    16,384
    float* k2    = q2    + (size_t)BH_ * T_;            //    16,384
    float* U     = k2    + (size_t)BH_ * T_;            // 2,097,152
    float* Uq    = U     + (size_t)BH_ * T_ * D_ * R_;  //    65,536
    // bf16 scratch after fp32 region
    unsigned short* xb  = (unsigned short*)(Uq + (size_t)BH_ * T_ * R_);
    unsigned short* wqb = xb  + (size_t)DM_ * DM_;
    unsigned short* wkb = wqb + (size_t)DM_ * DM_;
    unsigned short* wvb = wkb + (size_t)DM_ * DM_;
    unsigned short* wob = xb;                      // xb dead after qkv gemm
    unsigned short* ctxb = (unsigned short*)q_raw; // q_raw dead after feat

    convert_x_bf16<<<DM_ * DM_ / 1024, 256, 0, stream>>>(x, xb);
    transpose_w_bf16<<<dim3(16, 16, 3), 256, 0, stream>>>(Wq, Wk, Wv, wqb, wkb, wvb);
    mfma_gemm<0><<<dim3(24, 8), 256, 0, stream>>>(xb, wqb, wkb, wvb, q_raw, k_raw, v);
    feat_kernel<true ><<<BH_ * T_ / 4, 256, 0, stream>>>(q_raw, Wqm, Wmetric, qm, q2, U, Uq);
    feat_kernel<false><<<BH_ * T_ / 4, 256, 0, stream>>>(k_raw, Wkm, nullptr, km, k2, nullptr, nullptr);
    transpose_w_bf16<<<dim3(16, 16, 1), 256, 0, stream>>>(Wo, Wo, Wo, wob, wob, wob);
    fused_attn<<<dim3(T_ / 32, BH_), 256, 0, stream>>>(qm, km, q2, k2, U, Uq, temp, v, ctxb);
    mfma_gemm<1><<<dim3(8, 8), 256, 0, stream>>>(ctxb, wob, nullptr, nullptr, out, nullptr, nullptr);
}

// Round 6
// 250.590 us; speedup vs baseline: 2.2238x; 1.1078x over previous
//
#include <hip/hip_runtime.h>
#include <cmath>

// Problem constants
constexpr int B_  = 2;
constexpr int T_  = 512;
constexpr int DM_ = 1024;
constexpr int H_  = 16;
constexpr int DH_ = 64;
constexpr int D_  = 32;
constexpr int R_  = 4;
constexpr int BH_ = B_ * H_;   // 32

typedef __bf16 bf16x8 __attribute__((ext_vector_type(8)));
typedef float  f32x4  __attribute__((ext_vector_type(4)));
typedef unsigned short u16x8 __attribute__((ext_vector_type(8)));

__device__ __forceinline__ unsigned short f2bf(float f) {
    unsigned u = __float_as_uint(f);
    return (unsigned short)((u + 0x7fffu + ((u >> 16) & 1u)) >> 16);  // RNE
}

__device__ __forceinline__ void gload16(const void* g, void* l) {
    __builtin_amdgcn_global_load_lds(
        (const __attribute__((address_space(1))) void*)g,
        (__attribute__((address_space(3))) void*)l, 16, 0, 0);
}

// -------------------------------------------------------------------------
// Convert x (1M fp32) -> bf16 row-major.
// -------------------------------------------------------------------------
__global__ __launch_bounds__(256) void convert_x_bf16(
    const float* __restrict__ in, unsigned short* __restrict__ out)
{
    int idx = (blockIdx.x * 256 + threadIdx.x) * 4;
    float4 v = *(const float4*)&in[idx];
    ushort4 o = { f2bf(v.x), f2bf(v.y), f2bf(v.z), f2bf(v.w) };
    *(ushort4*)&out[idx] = o;
}

// -------------------------------------------------------------------------
// Transpose+convert W (1024x1024 fp32, K-major) -> out (N x K bf16).
// -------------------------------------------------------------------------
__global__ __launch_bounds__(256) void transpose_w_bf16(
    const float* __restrict__ W0, const float* __restrict__ W1,
    const float* __restrict__ W2,
    unsigned short* __restrict__ O0, unsigned short* __restrict__ O1,
    unsigned short* __restrict__ O2)
{
    __shared__ __align__(16) unsigned short Ls[64][72];
    const int z = blockIdx.z;
    const float* W = (z == 0) ? W0 : (z == 1) ? W1 : W2;
    unsigned short* O = (z == 0) ? O0 : (z == 1) ? O1 : O2;
    const int t  = threadIdx.x;
    const int k0 = blockIdx.x * 64;
    const int n0 = blockIdx.y * 64;
#pragma unroll
    for (int it = 0; it < 4; ++it) {
        int r = it * 16 + (t >> 4);
        int c = (t & 15) * 4;
        float4 v4 = *(const float4*)&W[(size_t)(k0 + r) * DM_ + n0 + c];
        Ls[c + 0][r] = f2bf(v4.x); Ls[c + 1][r] = f2bf(v4.y);
        Ls[c + 2][r] = f2bf(v4.z); Ls[c + 3][r] = f2bf(v4.w);
    }
    __syncthreads();
#pragma unroll
    for (int it = 0; it < 2; ++it) {
        int nl = it * 32 + (t >> 3);
        int kc = (t & 7) * 8;
        *(u16x8*)&O[(size_t)(n0 + nl) * DM_ + k0 + kc] = *(const u16x8*)&Ls[nl][kc];
    }
}

// -------------------------------------------------------------------------
// bf16 MFMA GEMM core (m97 style): 128x128 tile, BK=32, 256 thr.
// -------------------------------------------------------------------------
template <int EPI>
__global__ __launch_bounds__(256) void mfma_gemm(
    const unsigned short* __restrict__ A,
    const unsigned short* __restrict__ Bt0,
    const unsigned short* __restrict__ Bt1,
    const unsigned short* __restrict__ Bt2,
    float* __restrict__ C0, float* __restrict__ C1, float* __restrict__ C2)
{
    __shared__ __align__(16) unsigned short As[128 * 32];
    __shared__ __align__(16) unsigned short Bs[128 * 32];
    const int tid  = threadIdx.x;
    const int lane = tid & 63;
    const int w    = tid >> 6;
    const int wm   = (w & 1) * 64;
    const int wn   = (w >> 1) * 64;

    const int bm = blockIdx.y * 128;
    int bn;
    const unsigned short* Bt;
    float* C;
    if (EPI == 0) {
        int which = blockIdx.x >> 3;
        bn    = (blockIdx.x & 7) * 128;
        Bt = (which == 0) ? Bt0 : (which == 1) ? Bt1 : Bt2;
        C  = (which == 0) ? C0  : (which == 1) ? C1  : C2;
    } else {
        bn = blockIdx.x * 128;
        Bt = Bt0; C = C0;
    }

    f32x4 acc[4][4] = {};
    const int sr = tid >> 2;
    const int sc = (tid & 3) * 8;
    const unsigned short* Ap = A  + (size_t)(bm + sr) * DM_ + sc;
    const unsigned short* Bp = Bt + (size_t)(bn + sr) * DM_ + sc;
    unsigned short* AsP = &As[sr * 32 + sc];
    unsigned short* BsP = &Bs[sr * 32 + sc];
    const int fr = lane & 15;
    const int fq = (lane >> 4) * 8;

    for (int k0 = 0; k0 < DM_; k0 += 32) {
        gload16(Ap + k0,              AsP);
        gload16(Ap + 64 * DM_ + k0,   AsP + 64 * 32);
        gload16(Bp + k0,              BsP);
        gload16(Bp + 64 * DM_ + k0,   BsP + 64 * 32);
        __syncthreads();
        bf16x8 af[4], bfr[4];
#pragma unroll
        for (int i = 0; i < 4; ++i) {
            af[i]  = *(const bf16x8*)&As[(wm + i * 16 + fr) * 32 + fq];
            bfr[i] = *(const bf16x8*)&Bs[(wn + i * 16 + fr) * 32 + fq];
        }
#pragma unroll
        for (int mi = 0; mi < 4; ++mi)
#pragma unroll
            for (int ni = 0; ni < 4; ++ni)
                acc[mi][ni] = __builtin_amdgcn_mfma_f32_16x16x32_bf16(
                    af[mi], bfr[ni], acc[mi][ni], 0, 0, 0);
        __syncthreads();
    }

#pragma unroll
    for (int mi = 0; mi < 4; ++mi)
#pragma unroll
        for (int ni = 0; ni < 4; ++ni) {
            f32x4 a = acc[mi][ni];
            int col = bn + wn + ni * 16 + (lane & 15);
#pragma unroll
            for (int r = 0; r < 4; ++r) {
                int row = bm + wm + mi * 16 + (lane >> 4) * 4 + r;
                if (EPI == 0) {
                    int h = col >> 6, d = col & 63;
                    int bb = row >> 9, tt = row & (T_ - 1);
                    C[(((size_t)bb * H_ + h) * T_ + tt) * DH_ + d] = a[r];
                } else {
                    C[(size_t)row * DM_ + col] = a[r];
                }
            }
        }
}

// -------------------------------------------------------------------------
// Per-row features (unchanged).
// -------------------------------------------------------------------------
template <bool QSIDE>
__global__ __launch_bounds__(256) void feat_kernel(
    const float* __restrict__ raw, const float* __restrict__ Wm,
    const float* __restrict__ Wmetric,
    float* __restrict__ fm, float* __restrict__ f2,
    float* __restrict__ Ug, float* __restrict__ Uqg)
{
    __shared__ float qrs[4][64];
    __shared__ float qms[4][32];
    __shared__ float Us[4][128];
    const int tid  = threadIdx.x;
    const int w    = tid >> 6;
    const int lane = tid & 63;
    const int row  = blockIdx.x * 4 + w;
    const int t    = row & (T_ - 1);

    float rv = raw[(size_t)row * 64 + lane];
    int   fi = lane & 31;
    float ang = (float)t * expf((float)fi * -0.28782313662425575f);
    float s, c;
    sincosf(ang, &s, &c);
    float partner = __shfl_xor(rv, 32);
    float qr = (lane < 32) ? (rv * c - partner * s) : (partner * s + rv * c);
    qrs[w][lane] = qr;
    __syncthreads();

    if (lane < 32) {
        float acc = 0.f;
#pragma unroll 8
        for (int d = 0; d < 64; ++d) acc += qrs[w][d] * Wm[d * 32 + lane];
        float qv = 1.0f / (1.0f + __expf(-acc));
        qms[w][lane] = qv;
        fm[(size_t)row * 32 + lane] = qv;
    }
    __syncthreads();
    if (lane == 0) {
        float acc = 0.f;
#pragma unroll
        for (int m = 0; m < 32; ++m) acc += qms[w][m] * qms[w][m];
        f2[row] = acc;
    }
    if (QSIDE) {
        float a0 = 0.f, a1 = 0.f;
#pragma unroll 8
        for (int m = 0; m < 32; ++m) {
            float qv = qms[w][m];
            a0 += qv * Wmetric[m * 128 + lane];
            a1 += qv * Wmetric[m * 128 + 64 + lane];
        }
        Us[w][lane] = a0; Us[w][64 + lane] = a1;
        Ug[(size_t)row * 128 + lane]      = a0;
        Ug[(size_t)row * 128 + 64 + lane] = a1;
        __syncthreads();
        if (lane < 4) {
            float acc = 0.f;
#pragma unroll
            for (int d = 0; d < 32; ++d) acc += Us[w][d * 4 + lane] * qms[w][d];
            Uqg[(size_t)row * 4 + lane] = acc;
        }
    }
}

// -------------------------------------------------------------------------
// Split-j fused attention (flash-decoding style).
// Block (c=chunk of 128 j, itile of 32 i, bh).  Live iff c*4 <= itile.
// Computes partial (m, l, unnormalized O) over its chunk -> workspace.
// -------------------------------------------------------------------------
__global__ __launch_bounds__(256) void fused_attn_split(
    const float* __restrict__ qm, const float* __restrict__ km,
    const float* __restrict__ q2, const float* __restrict__ k2,
    const float* __restrict__ Ug, const float* __restrict__ Uqg,
    const float* __restrict__ temp_p, const float* __restrict__ v,
    float* __restrict__ Opart, float* __restrict__ Mpart,
    float* __restrict__ Lpart)
{
    __shared__ __align__(16) float qm_s[32][33];
    __shared__ __align__(16) float U_s[32][132];
    __shared__ __align__(16) float Uq_s[32][4];
    __shared__ float q2_s[32];
    __shared__ __align__(16) float kmT_s[32][36];
    __shared__ float k2_s[32];
    __shared__ __align__(16) float v_s[32][64];
    __shared__ float s_tile[32][33];

    const int c     = blockIdx.x;
    const int itile = blockIdx.y;
    const int bh    = blockIdx.z;
    if (c * 4 > itile) return;                        // dead block
    const int ntl = min(itile - c * 4, 3) + 1;        // 1..4 j-tiles
    const int i0  = itile * 32;
    const int tid = threadIdx.x;

    // ---- one-time staging of the i-tile ----
    for (int e = tid; e < 32 * 32; e += 256) {
        int ii = e >> 5, m = e & 31;
        qm_s[ii][m] = qm[((size_t)bh * T_ + i0 + ii) * 32 + m];
    }
    for (int e = tid; e < 32 * 128; e += 256) {
        int ii = e >> 7, n = e & 127;
        U_s[ii][n] = Ug[((size_t)bh * T_ + i0 + ii) * 128 + n];
    }
    if (tid < 128) Uq_s[tid >> 2][tid & 3] = Uqg[((size_t)bh * T_ + i0) * 4 + tid];
    if (tid < 32)  q2_s[tid] = q2[(size_t)bh * T_ + i0 + tid];

    const float inv_temp = 1.0f / fmaxf(temp_p[0], 0.5f);

    const int ii_s = tid & 31, js = tid >> 5;    // scores identity
    const int ii_u = tid >> 3, ds = tid & 7;     // update identity

    float m_run = -1e30f, l_run = 0.f;
    float O[8] = {};

    for (int jt = 0; jt < ntl; ++jt) {
        const int j0 = (c * 4 + jt) * 32;
        __syncthreads();
        // ---- stage km (transposed), k2, v tile ----
        {
            int jr = tid >> 3, c4 = (tid & 7) * 4;
            float4 g = *(const float4*)&km[((size_t)bh * T_ + j0 + jr) * 32 + c4];
            kmT_s[c4 + 0][jr] = g.x; kmT_s[c4 + 1][jr] = g.y;
            kmT_s[c4 + 2][jr] = g.z; kmT_s[c4 + 3][jr] = g.w;
        }
        if (tid < 32) k2_s[tid] = k2[(size_t)bh * T_ + j0 + tid];
#pragma unroll
        for (int e = tid; e < 512; e += 256) {
            int jr = e >> 4, c4 = (e & 15) * 4;
            *(float4*)&v_s[jr][c4] =
                *(const float4*)&v[((size_t)bh * T_ + j0 + jr) * 64 + c4];
        }
        __syncthreads();

        // ---- scores ----
        {
            float qk[4] = {};
            float ur[4][4] = {};
#pragma unroll 8
            for (int d = 0; d < 32; ++d) {
                float4 kd = *(const float4*)&kmT_s[d][js * 4];
                float  qv = qm_s[ii_s][d];
                float4 uv = *(const float4*)&U_s[ii_s][4 * d];
                float  kc[4] = {kd.x, kd.y, kd.z, kd.w};
#pragma unroll
                for (int cc = 0; cc < 4; ++cc) {
                    qk[cc] = fmaf(qv, kc[cc], qk[cc]);
                    ur[cc][0] = fmaf(uv.x, kc[cc], ur[cc][0]);
                    ur[cc][1] = fmaf(uv.y, kc[cc], ur[cc][1]);
                    ur[cc][2] = fmaf(uv.z, kc[cc], ur[cc][2]);
                    ur[cc][3] = fmaf(uv.w, kc[cc], ur[cc][3]);
                }
            }
            const float q2v = q2_s[ii_s];
            const float uq0 = Uq_s[ii_s][0], uq1 = Uq_s[ii_s][1];
            const float uq2 = Uq_s[ii_s][2], uq3 = Uq_s[ii_s][3];
#pragma unroll
            for (int cc = 0; cc < 4; ++cc) {
                int jj = js * 4 + cc;
                float e0 = uq0 - ur[cc][0], e1 = uq1 - ur[cc][1];
                float e2 = uq2 - ur[cc][2], e3 = uq3 - ur[cc][3];
                float dist = q2v + k2_s[jj] - 2.f * qk[cc]
                           + e0 * e0 + e1 * e1 + e2 * e2 + e3 * e3;
                float s = -fmaxf(dist, 0.f) * inv_temp;
                if (j0 + jj > i0 + ii_s) s = -1e30f;
                s_tile[ii_s][jj] = s;
            }
        }
        __syncthreads();

        // ---- online softmax + PV (rows fully masked so far produce
        //      garbage partials that the merge provably never reads) ----
        {
            float mt = -1e30f;
#pragma unroll 8
            for (int jj = 0; jj < 32; ++jj) mt = fmaxf(mt, s_tile[ii_u][jj]);
            float mnew  = fmaxf(m_run, mt);
            float alpha = __expf(m_run - mnew);
            l_run *= alpha;
#pragma unroll
            for (int dd = 0; dd < 8; ++dd) O[dd] *= alpha;
#pragma unroll 4
            for (int jj = 0; jj < 32; ++jj) {
                float p = __expf(s_tile[ii_u][jj] - mnew);
                l_run += p;
                float4 v0 = *(const float4*)&v_s[jj][ds * 8];
                float4 v1 = *(const float4*)&v_s[jj][ds * 8 + 4];
                O[0] = fmaf(p, v0.x, O[0]); O[1] = fmaf(p, v0.y, O[1]);
                O[2] = fmaf(p, v0.z, O[2]); O[3] = fmaf(p, v0.w, O[3]);
                O[4] = fmaf(p, v1.x, O[4]); O[5] = fmaf(p, v1.y, O[5]);
                O[6] = fmaf(p, v1.z, O[6]); O[7] = fmaf(p, v1.w, O[7]);
            }
            m_run = mnew;
        }
    }

    // ---- epilogue: write partials (unnormalized O, m, l) ----
    const int i = i0 + ii_u;
    const size_t rowix = ((size_t)c * BH_ + bh) * T_ + i;
    f32x4 o0 = {O[0], O[1], O[2], O[3]}, o1 = {O[4], O[5], O[6], O[7]};
    *(f32x4*)&Opart[rowix * 64 + ds * 8]     = o0;
    *(f32x4*)&Opart[rowix * 64 + ds * 8 + 4] = o1;
    if (ds == 0) { Mpart[rowix] = m_run; Lpart[rowix] = l_run; }
}

// -------------------------------------------------------------------------
// Merge <=4 partials per row; write ctx bf16 (b,t,c).
// Block (itile, bh); thread (ii=tid>>3, ds=tid&7).
// -------------------------------------------------------------------------
__global__ __launch_bounds__(256) void merge_attn(
    const float* __restrict__ Opart, const float* __restrict__ Mpart,
    const float* __restrict__ Lpart, unsigned short* __restrict__ ctxb)
{
    const int tid = threadIdx.x;
    const int itile = blockIdx.x, bh = blockIdx.y;
    const int ii = tid >> 3, ds = tid & 7;
    const int i = itile * 32 + ii;
    const int nc = (i >> 7) + 1;

    float mx = -1e30f;
    float mv[4];
    for (int c = 0; c < nc; ++c) {
        mv[c] = Mpart[((size_t)c * BH_ + bh) * T_ + i];
        mx = fmaxf(mx, mv[c]);
    }
    float lsum = 0.f;
    float O[8] = {};
    for (int c = 0; c < nc; ++c) {
        const size_t rowix = ((size_t)c * BH_ + bh) * T_ + i;
        float w = __expf(mv[c] - mx);
        lsum = fmaf(Lpart[rowix], w, lsum);
        float4 o0 = *(const float4*)&Opart[rowix * 64 + ds * 8];
        float4 o1 = *(const float4*)&Opart[rowix * 64 + ds * 8 + 4];
        O[0] = fmaf(w, o0.x, O[0]); O[1] = fmaf(w, o0.y, O[1]);
        O[2] = fmaf(w, o0.z, O[2]); O[3] = fmaf(w, o0.w, O[3]);
        O[4] = fmaf(w, o1.x, O[4]); O[5] = fmaf(w, o1.y, O[5]);
        O[6] = fmaf(w, o1.z, O[6]); O[7] = fmaf(w, o1.w, O[7]);
    }
    const float inv_l = 1.0f / lsum;
    const int b = bh >> 4, h = bh & 15;
    u16x8 o;
#pragma unroll
    for (int dd = 0; dd < 8; ++dd) o[dd] = f2bf(O[dd] * inv_l);
    *(u16x8*)&ctxb[((size_t)b * T_ + i) * DM_ + h * 64 + ds * 8] = o;
}

// -------------------------------------------------------------------------
extern "C" void kernel_launch(void* const* d_in, const int* in_sizes, int n_in,
                              void* d_out, int out_size, void* d_ws, size_t ws_size,
                              hipStream_t stream)
{
    const float* x       = (const float*)d_in[0];
    const float* Wq      = (const float*)d_in[1];
    const float* Wk      = (const float*)d_in[2];
    const float* Wv      = (const float*)d_in[3];
    const float* Wo      = (const float*)d_in[4];
    const float* Wqm     = (const float*)d_in[5];
    const float* Wkm     = (const float*)d_in[6];
    const float* Wmetric = (const float*)d_in[7];
    const float* temp    = (const float*)d_in[8];
    float* out = (float*)d_out;
    float* ws  = (float*)d_ws;

    // fp32 workspace (floats)
    float* q_raw = ws;                                  // 1,048,576
    float* k_raw = q_raw + (size_t)BH_ * T_ * DH_;      // 1,048,576
    float* v     = k_raw + (size_t)BH_ * T_ * DH_;      // 1,048,576
    float* qm    = v     + (size_t)BH_ * T_ * DH_;      //   524,288
    float* km    = qm    + (size_t)BH_ * T_ * D_;       //   524,288
    float* q2    = km    + (size_t)BH_ * T_ * D_;       //    16,384
    float* k2    = q2    + (size_t)BH_ * T_;            //    16,384
    float* U     = k2    + (size_t)BH_ * T_;            // 2,097,152
    float* Uq    = U     + (size_t)BH_ * T_ * D_ * R_;  //    65,536
    // bf16 scratch
    unsigned short* xb  = (unsigned short*)(Uq + (size_t)BH_ * T_ * R_);
    unsigned short* wqb = xb  + (size_t)DM_ * DM_;
    unsigned short* wkb = wqb + (size_t)DM_ * DM_;
    unsigned short* wvb = wkb + (size_t)DM_ * DM_;
    unsigned short* wob = xb;                      // xb dead after qkv gemm
    unsigned short* ctxb = (unsigned short*)q_raw; // q_raw dead after feat
    // split-attention partials (fp32), after bf16 region: 17.3 MB
    float* Opart = (float*)(wvb + (size_t)DM_ * DM_);   // 4*32*512*64
    float* Mpart = Opart + (size_t)4 * BH_ * T_ * DH_;  // 4*32*512
    float* Lpart = Mpart + (size_t)4 * BH_ * T_;

    convert_x_bf16<<<DM_ * DM_ / 1024, 256, 0, stream>>>(x, xb);
    transpose_w_bf16<<<dim3(16, 16, 3), 256, 0, stream>>>(Wq, Wk, Wv, wqb, wkb, wvb);
    mfma_gemm<0><<<dim3(24, 8), 256, 0, stream>>>(xb, wqb, wkb, wvb, q_raw, k_raw, v);
    feat_kernel<true ><<<BH_ * T_ / 4, 256, 0, stream>>>(q_raw, Wqm, Wmetric, qm, q2, U, Uq);
    feat_kernel<false><<<BH_ * T_ / 4, 256, 0, stream>>>(k_raw, Wkm, nullptr, km, k2, nullptr, nullptr);
    transpose_w_bf16<<<dim3(16, 16, 1), 256, 0, stream>>>(Wo, Wo, Wo, wob, wob, wob);
    fused_attn_split<<<dim3(4, 16, BH_), 256, 0, stream>>>(
        qm, km, q2, k2, U, Uq, temp, v, Opart, Mpart, Lpart);
    merge_attn<<<dim3(16, BH_), 256, 0, stream>>>(Opart, Mpart, Lpart, ctxb);
    mfma_gemm<1><<<dim3(8, 8), 256, 0, stream>>>(ctxb, wob, nullptr, nullptr, out, nullptr, nullptr);
}

// Round 7
// 225.195 us; speedup vs baseline: 2.4745x; 1.1128x over previous
//
#include <hip/hip_runtime.h>
#include <cmath>

// Problem constants
constexpr int B_  = 2;
constexpr int T_  = 512;
constexpr int DM_ = 1024;
constexpr int H_  = 16;
constexpr int DH_ = 64;
constexpr int D_  = 32;
constexpr int R_  = 4;
constexpr int BH_ = B_ * H_;   // 32

typedef __bf16 bf16x8 __attribute__((ext_vector_type(8)));
typedef float  f32x4  __attribute__((ext_vector_type(4)));
typedef unsigned short u16x8 __attribute__((ext_vector_type(8)));

__device__ __forceinline__ unsigned short f2bf(float f) {
    unsigned u = __float_as_uint(f);
    return (unsigned short)((u + 0x7fffu + ((u >> 16) & 1u)) >> 16);  // RNE
}

__device__ __forceinline__ void gload16(const void* g, void* l) {
    __builtin_amdgcn_global_load_lds(
        (const __attribute__((address_space(1))) void*)g,
        (__attribute__((address_space(3))) void*)l, 16, 0, 0);
}

// -------------------------------------------------------------------------
// Prep: z=0..3 -> transpose+convert Wq/Wk/Wv/Wo to (N x K) bf16;
//       z=4    -> convert x to bf16 row-major.
// -------------------------------------------------------------------------
__global__ __launch_bounds__(256) void prep_kernel(
    const float* __restrict__ x,
    const float* __restrict__ Wq, const float* __restrict__ Wk,
    const float* __restrict__ Wv, const float* __restrict__ Wo,
    unsigned short* __restrict__ xb,
    unsigned short* __restrict__ wqb, unsigned short* __restrict__ wkb,
    unsigned short* __restrict__ wvb, unsigned short* __restrict__ wob)
{
    const int t = threadIdx.x;
    const int z = blockIdx.z;
    if (z == 4) {
        // 256 blocks (16x16) x 4096 elems each, 16 per thread
        int base = (blockIdx.y * 16 + blockIdx.x) * 4096 + t * 16;
#pragma unroll
        for (int c = 0; c < 4; ++c) {
            float4 v = *(const float4*)&x[base + c * 4];
            ushort4 o = { f2bf(v.x), f2bf(v.y), f2bf(v.z), f2bf(v.w) };
            *(ushort4*)&xb[base + c * 4] = o;
        }
        return;
    }
    __shared__ __align__(16) unsigned short Ls[64][72];
    const float* W = (z == 0) ? Wq : (z == 1) ? Wk : (z == 2) ? Wv : Wo;
    unsigned short* O = (z == 0) ? wqb : (z == 1) ? wkb : (z == 2) ? wvb : wob;
    const int k0 = blockIdx.x * 64;
    const int n0 = blockIdx.y * 64;
#pragma unroll
    for (int it = 0; it < 4; ++it) {
        int r = it * 16 + (t >> 4);
        int c = (t & 15) * 4;
        float4 v4 = *(const float4*)&W[(size_t)(k0 + r) * DM_ + n0 + c];
        Ls[c + 0][r] = f2bf(v4.x); Ls[c + 1][r] = f2bf(v4.y);
        Ls[c + 2][r] = f2bf(v4.z); Ls[c + 3][r] = f2bf(v4.w);
    }
    __syncthreads();
#pragma unroll
    for (int it = 0; it < 2; ++it) {
        int nl = it * 32 + (t >> 3);
        int kc = (t & 7) * 8;
        *(u16x8*)&O[(size_t)(n0 + nl) * DM_ + k0 + kc] = *(const u16x8*)&Ls[nl][kc];
    }
}

// -------------------------------------------------------------------------
// 64x64-tile bf16 MFMA GEMM, BK=32, 256 thr (4 waves 2x2 of 32x32).
// High-occupancy variant for small M/N shapes (8 KB LDS, ~40 VGPR).
// EPI==0: scatter C into q/k/v head layout (N=3072 fused).  EPI==1: plain C.
// -------------------------------------------------------------------------
template <int EPI>
__global__ __launch_bounds__(256) void mfma_gemm64(
    const unsigned short* __restrict__ A,
    const unsigned short* __restrict__ Bt0,
    const unsigned short* __restrict__ Bt1,
    const unsigned short* __restrict__ Bt2,
    float* __restrict__ C0, float* __restrict__ C1, float* __restrict__ C2)
{
    __shared__ __align__(16) unsigned short As[64 * 32];
    __shared__ __align__(16) unsigned short Bs[64 * 32];
    const int tid  = threadIdx.x;
    const int lane = tid & 63;
    const int w    = tid >> 6;
    const int wm   = (w & 1) * 32;
    const int wn   = (w >> 1) * 32;

    const int bm = blockIdx.y * 64;
    int bn;
    const unsigned short* Bt;
    float* C;
    if (EPI == 0) {
        int n0 = blockIdx.x * 64;
        int which = n0 >> 10;
        bn = n0 & 1023;
        Bt = (which == 0) ? Bt0 : (which == 1) ? Bt1 : Bt2;
        C  = (which == 0) ? C0  : (which == 1) ? C1  : C2;
    } else {
        bn = blockIdx.x * 64;
        Bt = Bt0; C = C0;
    }

    f32x4 acc[2][2] = {};
    const int sr = tid >> 2;            // 0..63
    const int sc = (tid & 3) * 8;       // 16B chunk
    const unsigned short* Ap = A  + (size_t)(bm + sr) * DM_ + sc;
    const unsigned short* Bp = Bt + (size_t)(bn + sr) * DM_ + sc;
    unsigned short* AsP = &As[sr * 32 + sc];
    unsigned short* BsP = &Bs[sr * 32 + sc];
    const int fr = lane & 15;
    const int fq = (lane >> 4) * 8;

    for (int k0 = 0; k0 < DM_; k0 += 32) {
        gload16(Ap + k0, AsP);
        gload16(Bp + k0, BsP);
        __syncthreads();
        bf16x8 af[2], bfr[2];
#pragma unroll
        for (int i = 0; i < 2; ++i) {
            af[i]  = *(const bf16x8*)&As[(wm + i * 16 + fr) * 32 + fq];
            bfr[i] = *(const bf16x8*)&Bs[(wn + i * 16 + fr) * 32 + fq];
        }
#pragma unroll
        for (int mi = 0; mi < 2; ++mi)
#pragma unroll
            for (int ni = 0; ni < 2; ++ni)
                acc[mi][ni] = __builtin_amdgcn_mfma_f32_16x16x32_bf16(
                    af[mi], bfr[ni], acc[mi][ni], 0, 0, 0);
        __syncthreads();
    }

#pragma unroll
    for (int mi = 0; mi < 2; ++mi)
#pragma unroll
        for (int ni = 0; ni < 2; ++ni) {
            f32x4 a = acc[mi][ni];
            int col = bn + wn + ni * 16 + (lane & 15);
#pragma unroll
            for (int r = 0; r < 4; ++r) {
                int row = bm + wm + mi * 16 + (lane >> 4) * 4 + r;
                if (EPI == 0) {
                    int h = col >> 6, d = col & 63;
                    int bb = row >> 9, tt = row & (T_ - 1);
                    C[(((size_t)bb * H_ + h) * T_ + tt) * DH_ + d] = a[r];
                } else {
                    C[(size_t)row * DM_ + col] = a[r];
                }
            }
        }
}

// -------------------------------------------------------------------------
// Per-row features, q-side and k-side fused (blockIdx.y: 0=q, 1=k).
// -------------------------------------------------------------------------
__global__ __launch_bounds__(256) void feat_both(
    const float* __restrict__ q_raw, const float* __restrict__ k_raw,
    const float* __restrict__ Wqm,   const float* __restrict__ Wkm,
    const float* __restrict__ Wmetric,
    float* __restrict__ qm, float* __restrict__ km,
    float* __restrict__ q2, float* __restrict__ k2,
    float* __restrict__ Ug, float* __restrict__ Uqg)
{
    const bool QSIDE = (blockIdx.y == 0);
    const float* raw = QSIDE ? q_raw : k_raw;
    const float* Wm  = QSIDE ? Wqm   : Wkm;
    float* fm = QSIDE ? qm : km;
    float* f2 = QSIDE ? q2 : k2;

    __shared__ float qrs[4][64];
    __shared__ float qms[4][32];
    __shared__ float Us[4][128];
    const int tid  = threadIdx.x;
    const int w    = tid >> 6;
    const int lane = tid & 63;
    const int row  = blockIdx.x * 4 + w;
    const int t    = row & (T_ - 1);

    float rv = raw[(size_t)row * 64 + lane];
    int   fi = lane & 31;
    float ang = (float)t * expf((float)fi * -0.28782313662425575f);
    float s, c;
    sincosf(ang, &s, &c);
    float partner = __shfl_xor(rv, 32);
    float qr = (lane < 32) ? (rv * c - partner * s) : (partner * s + rv * c);
    qrs[w][lane] = qr;
    __syncthreads();

    if (lane < 32) {
        float acc = 0.f;
#pragma unroll 8
        for (int d = 0; d < 64; ++d) acc += qrs[w][d] * Wm[d * 32 + lane];
        float qv = 1.0f / (1.0f + __expf(-acc));
        qms[w][lane] = qv;
        fm[(size_t)row * 32 + lane] = qv;
    }
    __syncthreads();
    if (lane == 0) {
        float acc = 0.f;
#pragma unroll
        for (int m = 0; m < 32; ++m) acc += qms[w][m] * qms[w][m];
        f2[row] = acc;
    }
    if (QSIDE) {
        float a0 = 0.f, a1 = 0.f;
#pragma unroll 8
        for (int m = 0; m < 32; ++m) {
            float qv = qms[w][m];
            a0 += qv * Wmetric[m * 128 + lane];
            a1 += qv * Wmetric[m * 128 + 64 + lane];
        }
        Us[w][lane] = a0; Us[w][64 + lane] = a1;
        Ug[(size_t)row * 128 + lane]      = a0;
        Ug[(size_t)row * 128 + 64 + lane] = a1;
        __syncthreads();
        if (lane < 4) {
            float acc = 0.f;
#pragma unroll
            for (int d = 0; d < 32; ++d) acc += Us[w][d * 4 + lane] * qms[w][d];
            Uqg[(size_t)row * 4 + lane] = acc;
        }
    }
}

// -------------------------------------------------------------------------
// Split-j fused attention (unchanged from Round 6).
// -------------------------------------------------------------------------
__global__ __launch_bounds__(256) void fused_attn_split(
    const float* __restrict__ qm, const float* __restrict__ km,
    const float* __restrict__ q2, const float* __restrict__ k2,
    const float* __restrict__ Ug, const float* __restrict__ Uqg,
    const float* __restrict__ temp_p, const float* __restrict__ v,
    float* __restrict__ Opart, float* __restrict__ Mpart,
    float* __restrict__ Lpart)
{
    __shared__ __align__(16) float qm_s[32][33];
    __shared__ __align__(16) float U_s[32][132];
    __shared__ __align__(16) float Uq_s[32][4];
    __shared__ float q2_s[32];
    __shared__ __align__(16) float kmT_s[32][36];
    __shared__ float k2_s[32];
    __shared__ __align__(16) float v_s[32][64];
    __shared__ float s_tile[32][33];

    const int c     = blockIdx.x;
    const int itile = blockIdx.y;
    const int bh    = blockIdx.z;
    if (c * 4 > itile) return;                        // dead block
    const int ntl = min(itile - c * 4, 3) + 1;        // 1..4 j-tiles
    const int i0  = itile * 32;
    const int tid = threadIdx.x;

    for (int e = tid; e < 32 * 32; e += 256) {
        int ii = e >> 5, m = e & 31;
        qm_s[ii][m] = qm[((size_t)bh * T_ + i0 + ii) * 32 + m];
    }
    for (int e = tid; e < 32 * 128; e += 256) {
        int ii = e >> 7, n = e & 127;
        U_s[ii][n] = Ug[((size_t)bh * T_ + i0 + ii) * 128 + n];
    }
    if (tid < 128) Uq_s[tid >> 2][tid & 3] = Uqg[((size_t)bh * T_ + i0) * 4 + tid];
    if (tid < 32)  q2_s[tid] = q2[(size_t)bh * T_ + i0 + tid];

    const float inv_temp = 1.0f / fmaxf(temp_p[0], 0.5f);

    const int ii_s = tid & 31, js = tid >> 5;
    const int ii_u = tid >> 3, ds = tid & 7;

    float m_run = -1e30f, l_run = 0.f;
    float O[8] = {};

    for (int jt = 0; jt < ntl; ++jt) {
        const int j0 = (c * 4 + jt) * 32;
        __syncthreads();
        {
            int jr = tid >> 3, c4 = (tid & 7) * 4;
            float4 g = *(const float4*)&km[((size_t)bh * T_ + j0 + jr) * 32 + c4];
            kmT_s[c4 + 0][jr] = g.x; kmT_s[c4 + 1][jr] = g.y;
            kmT_s[c4 + 2][jr] = g.z; kmT_s[c4 + 3][jr] = g.w;
        }
        if (tid < 32) k2_s[tid] = k2[(size_t)bh * T_ + j0 + tid];
#pragma unroll
        for (int e = tid; e < 512; e += 256) {
            int jr = e >> 4, c4 = (e & 15) * 4;
            *(float4*)&v_s[jr][c4] =
                *(const float4*)&v[((size_t)bh * T_ + j0 + jr) * 64 + c4];
        }
        __syncthreads();

        {
            float qk[4] = {};
            float ur[4][4] = {};
#pragma unroll 8
            for (int d = 0; d < 32; ++d) {
                float4 kd = *(const float4*)&kmT_s[d][js * 4];
                float  qv = qm_s[ii_s][d];
                float4 uv = *(const float4*)&U_s[ii_s][4 * d];
                float  kc[4] = {kd.x, kd.y, kd.z, kd.w};
#pragma unroll
                for (int cc = 0; cc < 4; ++cc) {
                    qk[cc] = fmaf(qv, kc[cc], qk[cc]);
                    ur[cc][0] = fmaf(uv.x, kc[cc], ur[cc][0]);
                    ur[cc][1] = fmaf(uv.y, kc[cc], ur[cc][1]);
                    ur[cc][2] = fmaf(uv.z, kc[cc], ur[cc][2]);
                    ur[cc][3] = fmaf(uv.w, kc[cc], ur[cc][3]);
                }
            }
            const float q2v = q2_s[ii_s];
            const float uq0 = Uq_s[ii_s][0], uq1 = Uq_s[ii_s][1];
            const float uq2 = Uq_s[ii_s][2], uq3 = Uq_s[ii_s][3];
#pragma unroll
            for (int cc = 0; cc < 4; ++cc) {
                int jj = js * 4 + cc;
                float e0 = uq0 - ur[cc][0], e1 = uq1 - ur[cc][1];
                float e2 = uq2 - ur[cc][2], e3 = uq3 - ur[cc][3];
                float dist = q2v + k2_s[jj] - 2.f * qk[cc]
                           + e0 * e0 + e1 * e1 + e2 * e2 + e3 * e3;
                float s = -fmaxf(dist, 0.f) * inv_temp;
                if (j0 + jj > i0 + ii_s) s = -1e30f;
                s_tile[ii_s][jj] = s;
            }
        }
        __syncthreads();

        {
            float mt = -1e30f;
#pragma unroll 8
            for (int jj = 0; jj < 32; ++jj) mt = fmaxf(mt, s_tile[ii_u][jj]);
            float mnew  = fmaxf(m_run, mt);
            float alpha = __expf(m_run - mnew);
            l_run *= alpha;
#pragma unroll
            for (int dd = 0; dd < 8; ++dd) O[dd] *= alpha;
#pragma unroll 4
            for (int jj = 0; jj < 32; ++jj) {
                float p = __expf(s_tile[ii_u][jj] - mnew);
                l_run += p;
                float4 v0 = *(const float4*)&v_s[jj][ds * 8];
                float4 v1 = *(const float4*)&v_s[jj][ds * 8 + 4];
                O[0] = fmaf(p, v0.x, O[0]); O[1] = fmaf(p, v0.y, O[1]);
                O[2] = fmaf(p, v0.z, O[2]); O[3] = fmaf(p, v0.w, O[3]);
                O[4] = fmaf(p, v1.x, O[4]); O[5] = fmaf(p, v1.y, O[5]);
                O[6] = fmaf(p, v1.z, O[6]); O[7] = fmaf(p, v1.w, O[7]);
            }
            m_run = mnew;
        }
    }

    const int i = i0 + ii_u;
    const size_t rowix = ((size_t)c * BH_ + bh) * T_ + i;
    f32x4 o0 = {O[0], O[1], O[2], O[3]}, o1 = {O[4], O[5], O[6], O[7]};
    *(f32x4*)&Opart[rowix * 64 + ds * 8]     = o0;
    *(f32x4*)&Opart[rowix * 64 + ds * 8 + 4] = o1;
    if (ds == 0) { Mpart[rowix] = m_run; Lpart[rowix] = l_run; }
}

// -------------------------------------------------------------------------
// Merge <=4 partials per row; write ctx bf16 (b,t,c).
// -------------------------------------------------------------------------
__global__ __launch_bounds__(256) void merge_attn(
    const float* __restrict__ Opart, const float* __restrict__ Mpart,
    const float* __restrict__ Lpart, unsigned short* __restrict__ ctxb)
{
    const int tid = threadIdx.x;
    const int itile = blockIdx.x, bh = blockIdx.y;
    const int ii = tid >> 3, ds = tid & 7;
    const int i = itile * 32 + ii;
    const int nc = (i >> 7) + 1;

    float mx = -1e30f;
    float mv[4];
    for (int c = 0; c < nc; ++c) {
        mv[c] = Mpart[((size_t)c * BH_ + bh) * T_ + i];
        mx = fmaxf(mx, mv[c]);
    }
    float lsum = 0.f;
    float O[8] = {};
    for (int c = 0; c < nc; ++c) {
        const size_t rowix = ((size_t)c * BH_ + bh) * T_ + i;
        float w = __expf(mv[c] - mx);
        lsum = fmaf(Lpart[rowix], w, lsum);
        float4 o0 = *(const float4*)&Opart[rowix * 64 + ds * 8];
        float4 o1 = *(const float4*)&Opart[rowix * 64 + ds * 8 + 4];
        O[0] = fmaf(w, o0.x, O[0]); O[1] = fmaf(w, o0.y, O[1]);
        O[2] = fmaf(w, o0.z, O[2]); O[3] = fmaf(w, o0.w, O[3]);
        O[4] = fmaf(w, o1.x, O[4]); O[5] = fmaf(w, o1.y, O[5]);
        O[6] = fmaf(w, o1.z, O[6]); O[7] = fmaf(w, o1.w, O[7]);
    }
    const float inv_l = 1.0f / lsum;
    const int b = bh >> 4, h = bh & 15;
    u16x8 o;
#pragma unroll
    for (int dd = 0; dd < 8; ++dd) o[dd] = f2bf(O[dd] * inv_l);
    *(u16x8*)&ctxb[((size_t)b * T_ + i) * DM_ + h * 64 + ds * 8] = o;
}

// -------------------------------------------------------------------------
extern "C" void kernel_launch(void* const* d_in, const int* in_sizes, int n_in,
                              void* d_out, int out_size, void* d_ws, size_t ws_size,
                              hipStream_t stream)
{
    const float* x       = (const float*)d_in[0];
    const float* Wq      = (const float*)d_in[1];
    const float* Wk      = (const float*)d_in[2];
    const float* Wv      = (const float*)d_in[3];
    const float* Wo      = (const float*)d_in[4];
    const float* Wqm     = (const float*)d_in[5];
    const float* Wkm     = (const float*)d_in[6];
    const float* Wmetric = (const float*)d_in[7];
    const float* temp    = (const float*)d_in[8];
    float* out = (float*)d_out;
    float* ws  = (float*)d_ws;

    // fp32 workspace (floats)
    float* q_raw = ws;                                  // 1,048,576
    float* k_raw = q_raw + (size_t)BH_ * T_ * DH_;      // 1,048,576
    float* v     = k_raw + (size_t)BH_ * T_ * DH_;      // 1,048,576
    float* qm    = v     + (size_t)BH_ * T_ * DH_;      //   524,288
    float* km    = qm    + (size_t)BH_ * T_ * D_;       //   524,288
    float* q2    = km    + (size_t)BH_ * T_ * D_;       //    16,384
    float* k2    = q2    + (size_t)BH_ * T_;            //    16,384
    float* U     = k2    + (size_t)BH_ * T_;            // 2,097,152
    float* Uq    = U     + (size_t)BH_ * T_ * D_ * R_;  //    65,536
    // bf16 scratch
    unsigned short* xb  = (unsigned short*)(Uq + (size_t)BH_ * T_ * R_);
    unsigned short* wqb = xb  + (size_t)DM_ * DM_;
    unsigned short* wkb = wqb + (size_t)DM_ * DM_;
    unsigned short* wvb = wkb + (size_t)DM_ * DM_;
    unsigned short* ctxb = (unsigned short*)q_raw;      // q_raw dead after feat
    // split-attention partials + separate Wo buffer (total ~52.9 MB)
    float* Opart = (float*)(wvb + (size_t)DM_ * DM_);   // 4*32*512*64
    float* Mpart = Opart + (size_t)4 * BH_ * T_ * DH_;  // 4*32*512
    float* Lpart = Mpart + (size_t)4 * BH_ * T_;
    unsigned short* wob = (unsigned short*)(Lpart + (size_t)4 * BH_ * T_);

    prep_kernel<<<dim3(16, 16, 5), 256, 0, stream>>>(
        x, Wq, Wk, Wv, Wo, xb, wqb, wkb, wvb, wob);
    mfma_gemm64<0><<<dim3(48, 16), 256, 0, stream>>>(
        xb, wqb, wkb, wvb, q_raw, k_raw, v);
    feat_both<<<dim3(BH_ * T_ / 4, 2), 256, 0, stream>>>(
        q_raw, k_raw, Wqm, Wkm, Wmetric, qm, km, q2, k2, U, Uq);
    fused_attn_split<<<dim3(4, 16, BH_), 256, 0, stream>>>(
        qm, km, q2, k2, U, Uq, temp, v, Opart, Mpart, Lpart);
    merge_attn<<<dim3(16, BH_), 256, 0, stream>>>(Opart, Mpart, Lpart, ctxb);
    mfma_gemm64<1><<<dim3(16, 16), 256, 0, stream>>>(
        ctxb, wob, nullptr, nullptr, out, nullptr, nullptr);
}